// Round 5
// baseline (893.886 us; speedup 1.0000x reference)
//
#include <hip/hip_runtime.h>
#include <math.h>

#define NROWS 512
#define NSTEPS 256

// Single fused kernel: one wave per column, lane l owns rows 8l..8l+7.
// No workspace, no static __device__ data, no LDS, no __syncthreads.
// Epilogue writes exactly out_size floats — round 1-4 aborts are attributed
// to writing 2 MB complex into a 1 MB (262144-float, real-part) d_out.

__device__ __forceinline__ void cmul(float2& v, float ar, float ai) {
  float xr = ar * v.x - ai * v.y;
  float xi = ar * v.y + ai * v.x;
  v.x = xr; v.y = xi;
}
// top' = t*top + i r*bot ; bot' = i r*top + t*bot   (t, r real)
__device__ __forceinline__ void mmix(float2& top, float2& bot, float t, float r) {
  float a = t * top.x - r * bot.y;
  float b = t * top.y + r * bot.x;
  float c = t * bot.x - r * top.y;
  float d = t * bot.y + r * top.x;
  top.x = a; top.y = b; bot.x = c; bot.y = d;
}

__global__ __launch_bounds__(256) void fused_kernel(
    const float* __restrict__ thf,  const float* __restrict__ thio,
    const float* __restrict__ lpf,  const float* __restrict__ lpio,
    const float* __restrict__ le,   const float* __restrict__ lo,
    const float* __restrict__ ie,   const float* __restrict__ io2,
    float* __restrict__ out, int write_complex) {
  const int l   = threadIdx.x & 63;
  const int col = blockIdx.x * 4 + (threadIdx.x >> 6);
  const int r0  = 8 * l;

  // M = I : column col has a single 1 at row col.
  float2 v[8];
  #pragma unroll
  for (int k = 0; k < 8; ++k)
    v[k] = (col == r0 + k) ? make_float2(1.0f, 0.0f) : make_float2(0.0f, 0.0f);

  // phase-shifter layer from a theta/loss row pointer (512 entries)
  auto pc_row = [&](const float* th, const float* lp) {
    #pragma unroll
    for (int k = 0; k < 8; ++k) {
      float a = sqrtf(1.0f - lp[r0 + k]);
      float t = th[r0 + k];
      float s = __sinf(t);
      float c = __cosf(t);
      cmul(v[k], a * c, a * s);
    }
  };
  // even MMI layer L: pairs (2k,2k+1); lane handles pairs 4l..4l+3, all internal
  auto even_l = [&](int L) {
    const float* pl = le + L * 256 + 4 * l;
    const float* pi = ie + L * 256 + 4 * l;
    #pragma unroll
    for (int j = 0; j < 4; ++j) {
      float a = sqrtf(1.0f - pl[j]);
      float t = a * sqrtf(0.5f + pi[j]);
      float r = a * sqrtf(0.5f - pi[j]);
      mmix(v[2 * j], v[2 * j + 1], t, r);
    }
  };
  // odd MMI layer L: pairs (2k+1,2k+2), k=0..254; rows 0 and 511 pass through.
  auto odd_l = [&](int L) {
    // old neighbor state, gathered before any update
    float nbx = __shfl_down(v[0].x, 1);  // lane l+1's row 8l+8 (bot of my v7 pair)
    float nby = __shfl_down(v[0].y, 1);
    float ptx = __shfl_up(v[7].x, 1);    // lane l-1's row 8l-1 (top of my v0 pair)
    float pty = __shfl_up(v[7].y, 1);
    const float* pl = lo  + L * 255;
    const float* pi = io2 + L * 255;
    float t[4], r[4];
    #pragma unroll
    for (int j = 0; j < 4; ++j) {
      int k = 4 * l + j;
      if (k > 254) k = 254;              // lane 63, j=3: clamp (value unused)
      float a = sqrtf(1.0f - pl[k]);
      t[j] = a * sqrtf(0.5f + pi[k]);
      r[j] = a * sqrtf(0.5f - pi[k]);
    }
    float cpt = __shfl_up(t[3], 1);      // coeff of pair 4(l-1)+3 (my v0's pair)
    float cpr = __shfl_up(r[3], 1);
    // internal pairs (8l+1,8l+2),(8l+3,8l+4),(8l+5,8l+6)
    mmix(v[1], v[2], t[0], r[0]);
    mmix(v[3], v[4], t[1], r[1]);
    mmix(v[5], v[6], t[2], r[2]);
    // boundary pair (8l+7, 8l+8): my v7 is TOP; skip l==63 (row 511 passes)
    if (l != 63) {
      float xr = t[3] * v[7].x - r[3] * nby;
      float xi = t[3] * v[7].y + r[3] * nbx;
      v[7].x = xr; v[7].y = xi;
    }
    // boundary pair (8l-1, 8l): my v0 is BOT; skip l==0 (row 0 passes)
    if (l != 0) {
      float xr = cpt * v[0].x - cpr * pty;
      float xi = cpt * v[0].y + cpr * ptx;
      v[0].x = xr; v[0].y = xi;
    }
  };

  pc_row(thio, lpio);                    // Pin (row 0 of thetas_inout)
  #pragma unroll 1
  for (int i = 0; i < NSTEPS; ++i) {
    even_l(2 * i);
    pc_row(thf + (2 * i) * 512, lpf + (2 * i) * 512);
    even_l(2 * i + 1);
    odd_l(2 * i);
    pc_row(thf + (2 * i + 1) * 512, lpf + (2 * i + 1) * 512);
    odd_l(2 * i + 1);
  }
  pc_row(thio + 512, lpio + 512);        // Pout (row 1)

  if (write_complex) {
    float2* o = (float2*)out;            // out_size = 524288 floats (2 MB)
    #pragma unroll
    for (int k = 0; k < 8; ++k)
      o[(r0 + k) * NROWS + col] = v[k];
  } else {
    // out_size = 262144 floats (1 MB): real part only (complex64 ref reduced
    // to float32 by the harness).
    #pragma unroll
    for (int k = 0; k < 8; ++k)
      out[(r0 + k) * NROWS + col] = v[k].x;
  }
}

extern "C" void kernel_launch(void* const* d_in, const int* in_sizes, int n_in,
                              void* d_out, int out_size, void* d_ws, size_t ws_size,
                              hipStream_t stream) {
  const float* thf  = (const float*)d_in[0];  // thetas_full     (512,512)
  const float* thio = (const float*)d_in[1];  // thetas_inout    (2,512)
  const float* lpf  = (const float*)d_in[2];  // pc_losses_full  (512,512)
  const float* lpio = (const float*)d_in[3];  // pc_losses_inout (2,512)
  const float* le   = (const float*)d_in[4];  // mmi_losses_even (512,256)
  const float* lo   = (const float*)d_in[5];  // mmi_losses_odd  (512,255)
  const float* ie   = (const float*)d_in[6];  // mmi_imb_even    (512,256)
  const float* io2  = (const float*)d_in[7];  // mmi_imb_odd     (512,255)

  const int write_complex = (out_size >= 2 * NROWS * NROWS) ? 1 : 0;

  fused_kernel<<<128, 256, 0, stream>>>(thf, thio, lpf, lpio, le, lo, ie, io2,
                                        (float*)d_out, write_complex);
}

// Round 6
// 483.819 us; speedup vs baseline: 1.8476x; 1.8476x over previous
//
#include <hip/hip_runtime.h>
#include <math.h>

#define NROWS  512
#define NSTEPS 256
#define STEP_F2 2048
#define TOTAL_F2 (512 + NSTEPS*STEP_F2 + 512)

// Layer-ordered coefficient stream (~4.2 MB) in static device memory,
// rewritten from inputs on every call. Layout (float2 entries):
//  [0,512)                 : Pin  (a per row)
//  per step i (base 512+i*2048):
//    +0    : E(2i)   256 pairs (t,r)
//    +256  : P(2i)   512 rows  (a)
//    +768  : E(2i+1) 256 pairs
//    +1024 : O(2i)   255 pairs + 1 pad (1,0)
//    +1280 : P(2i+1) 512 rows
//    +1792 : O(2i+1) 255 pairs + 1 pad (1,0)
//  [512+256*2048, +512)    : Pout
__device__ alignas(16) float2 g_ws[TOTAL_F2];

// ---------------- coefficient precompute ----------------

__device__ __forceinline__ float2 pc_coef(float th, float loss) {
  float a = sqrtf(1.0f - loss);
  float s, c;
  sincosf(th, &s, &c);
  return make_float2(a * c, a * s);
}
__device__ __forceinline__ float2 mmi_coef(float loss, float imb) {
  float a = sqrtf(1.0f - loss);
  return make_float2(a * sqrtf(0.5f + imb), a * sqrtf(0.5f - imb));
}

__global__ void precomp_kernel(const float* __restrict__ thf,
                               const float* __restrict__ thio,
                               const float* __restrict__ lpf,
                               const float* __restrict__ lpio,
                               const float* __restrict__ le,
                               const float* __restrict__ lo,
                               const float* __restrict__ ie,
                               const float* __restrict__ io2) {
  int idx = blockIdx.x * 256 + threadIdx.x;
  if (idx >= TOTAL_F2) return;
  float2 v;
  if (idx < 512) {
    v = pc_coef(thio[idx], lpio[idx]);
  } else if (idx >= 512 + NSTEPS * STEP_F2) {
    int r = idx - (512 + NSTEPS * STEP_F2);
    v = pc_coef(thio[512 + r], lpio[512 + r]);
  } else {
    int rel = idx - 512;
    int i = rel >> 11;
    int pos = rel & 2047;
    if (pos < 256) {
      int L = 2 * i, pr = pos;
      v = mmi_coef(le[L * 256 + pr], ie[L * 256 + pr]);
    } else if (pos < 768) {
      int L = 2 * i, r = pos - 256;
      v = pc_coef(thf[L * 512 + r], lpf[L * 512 + r]);
    } else if (pos < 1024) {
      int L = 2 * i + 1, pr = pos - 768;
      v = mmi_coef(le[L * 256 + pr], ie[L * 256 + pr]);
    } else if (pos < 1280) {
      int L = 2 * i, pr = pos - 1024;
      v = (pr < 255) ? mmi_coef(lo[L * 255 + pr], io2[L * 255 + pr])
                     : make_float2(1.0f, 0.0f);
    } else if (pos < 1792) {
      int L = 2 * i + 1, r = pos - 1280;
      v = pc_coef(thf[L * 512 + r], lpf[L * 512 + r]);
    } else {
      int L = 2 * i + 1, pr = pos - 1792;
      v = (pr < 255) ? mmi_coef(lo[L * 255 + pr], io2[L * 255 + pr])
                     : make_float2(1.0f, 0.0f);
    }
  }
  g_ws[idx] = v;
}

// ---------------- column propagation ----------------
// Block = 256 threads = 4 waves = one column PAIR (colbase, colbase+1).
// Wave w owns rows 128w..128w+127; lane l owns rows R0=128w+2l, R0+1 of BOTH
// columns (8 VGPR state). Coefficients loaded once per lane, shared by the
// two columns. Even pairs lane-internal; odd pairs couple to lane+-1 via
// shuffle, wave-boundary rows via LDS (parity-double-buffered, 1 barrier per
// odd layer).

__device__ __forceinline__ void cmul(float2& v, float ar, float ai) {
  float xr = ar * v.x - ai * v.y;
  float xi = ar * v.y + ai * v.x;
  v.x = xr; v.y = xi;
}
// top' = t*top + i r*bot ; bot' = i r*top + t*bot   (t, r real)
__device__ __forceinline__ void mmix(float2& top, float2& bot, float t, float r) {
  float a = t * top.x - r * bot.y;
  float b = t * top.y + r * bot.x;
  float c = t * bot.x - r * top.y;
  float d = t * bot.y + r * top.x;
  top.x = a; top.y = b; bot.x = c; bot.y = d;
}
// v' = t*v + i r*o
__device__ __forceinline__ void upd(float2& v, float2 c, float2 o) {
  float xr = c.x * v.x - c.y * o.y;
  float xi = c.x * v.y + c.y * o.x;
  v.x = xr; v.y = xi;
}

__global__ __launch_bounds__(256) void prop_kernel(float* __restrict__ out,
                                                   int write_complex) {
  __shared__ float2 sUp[2][2][4];  // [col][sid][wave] old row1 of lane 63 (row 128w+127)
  __shared__ float2 sDn[2][2][4];  // [col][sid][wave] old row0 of lane 0  (row 128w)
  const int l  = threadIdx.x & 63;
  const int w  = threadIdx.x >> 6;
  const int R0 = 128 * w + 2 * l;
  const int colbase = blockIdx.x * 2;

  float2 v[2][2];  // [col][row-in-lane]
  #pragma unroll
  for (int c = 0; c < 2; ++c)
    #pragma unroll
    for (int k = 0; k < 2; ++k)
      v[c][k] = (colbase + c == R0 + k) ? make_float2(1.0f, 0.0f)
                                        : make_float2(0.0f, 0.0f);

  auto pc_layer = [&](const float2* q) {
    float4 a = *(const float4*)(q + R0);     // rows R0, R0+1
    cmul(v[0][0], a.x, a.y); cmul(v[1][0], a.x, a.y);
    cmul(v[0][1], a.z, a.w); cmul(v[1][1], a.z, a.w);
  };
  auto even_layer = [&](const float2* q) {
    float2 c = q[64 * w + l];                // pair (R0, R0+1)
    mmix(v[0][0], v[0][1], c.x, c.y);
    mmix(v[1][0], v[1][1], c.x, c.y);
  };
  auto odd_layer = [&](const float2* q, int sid) {
    // old neighbor state (gather before any update)
    float2 nb0, nb1, pt0, pt1;
    nb0.x = __shfl_down(v[0][0].x, 1); nb0.y = __shfl_down(v[0][0].y, 1);
    nb1.x = __shfl_down(v[1][0].x, 1); nb1.y = __shfl_down(v[1][0].y, 1);
    pt0.x = __shfl_up(v[0][1].x, 1);   pt0.y = __shfl_up(v[0][1].y, 1);
    pt1.x = __shfl_up(v[1][1].x, 1);   pt1.y = __shfl_up(v[1][1].y, 1);
    if (l == 0)  { sDn[0][sid][w] = v[0][0]; sDn[1][sid][w] = v[1][0]; }
    if (l == 63) { sUp[0][sid][w] = v[0][1]; sUp[1][sid][w] = v[1][1]; }
    __syncthreads();
    if (l == 63 && w < 3) { nb0 = sDn[0][sid][w + 1]; nb1 = sDn[1][sid][w + 1]; }
    if (l == 0 && w > 0)  { pt0 = sUp[0][sid][w - 1]; pt1 = sUp[1][sid][w - 1]; }
    // coeffs: my row1 is TOP of pair kT = 64w+l; my row0 is BOT of kB = kT-1
    float2 cT = q[64 * w + l];
    float2 cB; cB.x = __shfl_up(cT.x, 1); cB.y = __shfl_up(cT.y, 1);
    if (l == 0 && w > 0) cB = q[64 * w - 1];
    if (!(w == 3 && l == 63)) {            // global row 511 passes through
      upd(v[0][1], cT, nb0);
      upd(v[1][1], cT, nb1);
    }
    if (!(w == 0 && l == 0)) {             // global row 0 passes through
      upd(v[0][0], cB, pt0);
      upd(v[1][0], cB, pt1);
    }
  };

  const float2* p = g_ws;
  pc_layer(p);                 // Pin
  p += 512;
  #pragma unroll 1
  for (int i = 0; i < NSTEPS; ++i) {
    even_layer(p);             // E(2i)
    pc_layer(p + 256);         // P(2i)
    even_layer(p + 768);       // E(2i+1)
    odd_layer(p + 1024, 0);    // O(2i)
    pc_layer(p + 1280);        // P(2i+1)
    odd_layer(p + 1792, 1);    // O(2i+1)
    p += STEP_F2;
  }
  pc_layer(p);                 // Pout

  if (write_complex) {
    float2* o = (float2*)out;
    #pragma unroll
    for (int c = 0; c < 2; ++c) {
      o[(R0 + 0) * NROWS + colbase + c] = v[c][0];
      o[(R0 + 1) * NROWS + colbase + c] = v[c][1];
    }
  } else {
    // d_out = 262144 floats: real part of the complex64 matrix
    #pragma unroll
    for (int c = 0; c < 2; ++c) {
      out[(R0 + 0) * NROWS + colbase + c] = v[c][0].x;
      out[(R0 + 1) * NROWS + colbase + c] = v[c][1].x;
    }
  }
}

// ---------------- launch ----------------

extern "C" void kernel_launch(void* const* d_in, const int* in_sizes, int n_in,
                              void* d_out, int out_size, void* d_ws, size_t ws_size,
                              hipStream_t stream) {
  const float* thf  = (const float*)d_in[0];  // thetas_full     (512,512)
  const float* thio = (const float*)d_in[1];  // thetas_inout    (2,512)
  const float* lpf  = (const float*)d_in[2];  // pc_losses_full  (512,512)
  const float* lpio = (const float*)d_in[3];  // pc_losses_inout (2,512)
  const float* le   = (const float*)d_in[4];  // mmi_losses_even (512,256)
  const float* lo   = (const float*)d_in[5];  // mmi_losses_odd  (512,255)
  const float* ie   = (const float*)d_in[6];  // mmi_imb_even    (512,256)
  const float* io2  = (const float*)d_in[7];  // mmi_imb_odd     (512,255)

  const int write_complex = (out_size >= 2 * NROWS * NROWS) ? 1 : 0;

  precomp_kernel<<<(TOTAL_F2 + 255) / 256, 256, 0, stream>>>(
      thf, thio, lpf, lpio, le, lo, ie, io2);
  prop_kernel<<<NROWS / 2, 256, 0, stream>>>((float*)d_out, write_complex);
}

// Round 7
// 220.139 us; speedup vs baseline: 4.0605x; 2.1978x over previous
//
#include <hip/hip_runtime.h>
#include <math.h>

#define NROWS   512
#define NSTEPS  256
#define PKSTEPS (NSTEPS + 2)   // +2 pad steps so prefetch can overrun unguarded

// Packet stream: [step][slot 0..4][tid 0..255] float4, slot-major per step so
// each wave's load of one slot is 64 consecutive float4 (perfect coalescing).
//  slot0 = (E0.t, E0.r, E1.t, E1.r)          even-layer coeffs, pair 64w+l
//  slot1 = (P0[R0].re, .im, P0[R0+1].re, .im) phase layer 2i
//  slot2 = (O0 cT.t, cT.r, cB.t, cB.r)        odd layer 2i (cB = pair-1, baked in)
//  slot3 = P1 rows                            phase layer 2i+1
//  slot4 = O1 cT/cB                           odd layer 2i+1
__device__ float4 g_pk[PKSTEPS * 5 * 256];
__device__ float2 g_io[1024];   // [0,512) = Pin per row, [512,1024) = Pout per row

// ---------------- coefficient precompute ----------------

__device__ __forceinline__ float2 pc_coef(float th, float loss) {
  float a = sqrtf(1.0f - loss);
  float s, c;
  sincosf(th, &s, &c);
  return make_float2(a * c, a * s);
}
__device__ __forceinline__ float2 mmi_coef(float loss, float imb) {
  float a = sqrtf(1.0f - loss);
  return make_float2(a * sqrtf(0.5f + imb), a * sqrtf(0.5f - imb));
}

__global__ void precomp_kernel(const float* __restrict__ thf,
                               const float* __restrict__ thio,
                               const float* __restrict__ lpf,
                               const float* __restrict__ lpio,
                               const float* __restrict__ le,
                               const float* __restrict__ lo,
                               const float* __restrict__ ie,
                               const float* __restrict__ io2) {
  const int b   = blockIdx.x;
  const int tid = threadIdx.x;
  if (b >= NSTEPS) {
    // io blocks: j in [0,512); thio/lpio are (2,512) flattened
    int j = (b - NSTEPS) * 256 + tid;
    g_io[j]       = pc_coef(thio[j],       lpio[j]);        // Pin
    g_io[j + 512] = pc_coef(thio[j + 512], lpio[j + 512]);  // Pout
    return;
  }
  const int i  = b;
  const int w  = tid >> 6, l = tid & 63;
  const int R0 = 128 * w + 2 * l;
  const int p  = 64 * w + l;
  const int L0 = 2 * i, L1 = 2 * i + 1;

  float2 e0  = mmi_coef(le[L0 * 256 + p], ie[L0 * 256 + p]);
  float2 e1  = mmi_coef(le[L1 * 256 + p], ie[L1 * 256 + p]);
  float2 p0a = pc_coef(thf[L0 * 512 + R0],     lpf[L0 * 512 + R0]);
  float2 p0b = pc_coef(thf[L0 * 512 + R0 + 1], lpf[L0 * 512 + R0 + 1]);
  float2 p1a = pc_coef(thf[L1 * 512 + R0],     lpf[L1 * 512 + R0]);
  float2 p1b = pc_coef(thf[L1 * 512 + R0 + 1], lpf[L1 * 512 + R0 + 1]);
  float2 one = make_float2(1.0f, 0.0f);
  float2 o0T = (p <= 254) ? mmi_coef(lo[L0 * 255 + p],     io2[L0 * 255 + p])     : one;
  float2 o0B = (p >= 1)   ? mmi_coef(lo[L0 * 255 + p - 1], io2[L0 * 255 + p - 1]) : one;
  float2 o1T = (p <= 254) ? mmi_coef(lo[L1 * 255 + p],     io2[L1 * 255 + p])     : one;
  float2 o1B = (p >= 1)   ? mmi_coef(lo[L1 * 255 + p - 1], io2[L1 * 255 + p - 1]) : one;

  float4* base = g_pk + (i * 5) * 256 + tid;
  base[0]        = make_float4(e0.x,  e0.y,  e1.x,  e1.y);
  base[256]      = make_float4(p0a.x, p0a.y, p0b.x, p0b.y);
  base[2 * 256]  = make_float4(o0T.x, o0T.y, o0B.x, o0B.y);
  base[3 * 256]  = make_float4(p1a.x, p1a.y, p1b.x, p1b.y);
  base[4 * 256]  = make_float4(o1T.x, o1T.y, o1B.x, o1B.y);
}

// ---------------- column propagation ----------------
// Block = 256 threads = 4 waves = one column PAIR. Wave w owns rows
// 128w..128w+127; lane l owns rows R0=128w+2l, R0+1 of both columns.
// 2-step-ahead register prefetch of the 5-float4 packet hides L2/HBM latency.

__device__ __forceinline__ void cmul(float2& v, float ar, float ai) {
  float xr = ar * v.x - ai * v.y;
  float xi = ar * v.y + ai * v.x;
  v.x = xr; v.y = xi;
}
__device__ __forceinline__ void mmix(float2& top, float2& bot, float t, float r) {
  float a = t * top.x - r * bot.y;
  float b = t * top.y + r * bot.x;
  float c = t * bot.x - r * top.y;
  float d = t * bot.y + r * top.x;
  top.x = a; top.y = b; bot.x = c; bot.y = d;
}
// v' = t*v + i r*o
__device__ __forceinline__ void upd(float2& v, float t, float r, float2 o) {
  float xr = t * v.x - r * o.y;
  float xi = t * v.y + r * o.x;
  v.x = xr; v.y = xi;
}

__global__ __launch_bounds__(256) void prop_kernel(float* __restrict__ out,
                                                   int write_complex) {
  __shared__ float2 sUp[2][2][4];  // [col][sid][wave]: old row 128w+127
  __shared__ float2 sDn[2][2][4];  // [col][sid][wave]: old row 128w
  const int tid = threadIdx.x;
  const int l = tid & 63, w = tid >> 6;
  const int R0 = 128 * w + 2 * l;
  const int colbase = blockIdx.x * 2;

  float2 v[2][2];  // [col][row-in-lane], constant indices only
  #pragma unroll
  for (int c = 0; c < 2; ++c)
    #pragma unroll
    for (int k = 0; k < 2; ++k)
      v[c][k] = (colbase + c == R0 + k) ? make_float2(1.0f, 0.0f)
                                        : make_float2(0.0f, 0.0f);

  auto odd = [&](float4 c, int sid) {
    // old neighbor state, gathered before any update
    float2 nb0, nb1, pt0, pt1;
    nb0.x = __shfl_down(v[0][0].x, 1); nb0.y = __shfl_down(v[0][0].y, 1);
    nb1.x = __shfl_down(v[1][0].x, 1); nb1.y = __shfl_down(v[1][0].y, 1);
    pt0.x = __shfl_up(v[0][1].x, 1);   pt0.y = __shfl_up(v[0][1].y, 1);
    pt1.x = __shfl_up(v[1][1].x, 1);   pt1.y = __shfl_up(v[1][1].y, 1);
    if (l == 0)  { sDn[0][sid][w] = v[0][0]; sDn[1][sid][w] = v[1][0]; }
    if (l == 63) { sUp[0][sid][w] = v[0][1]; sUp[1][sid][w] = v[1][1]; }
    __syncthreads();
    if (l == 63 && w < 3) { nb0 = sDn[0][sid][w + 1]; nb1 = sDn[1][sid][w + 1]; }
    if (l == 0 && w > 0)  { pt0 = sUp[0][sid][w - 1]; pt1 = sUp[1][sid][w - 1]; }
    if (!(w == 3 && l == 63)) {          // row 511 passes through
      upd(v[0][1], c.x, c.y, nb0);
      upd(v[1][1], c.x, c.y, nb1);
    }
    if (!(w == 0 && l == 0)) {           // row 0 passes through
      upd(v[0][0], c.z, c.w, pt0);
      upd(v[1][0], c.z, c.w, pt1);
    }
  };

  auto step = [&](float4 f0, float4 f1, float4 f2, float4 f3, float4 f4) {
    // E(2i)
    mmix(v[0][0], v[0][1], f0.x, f0.y);
    mmix(v[1][0], v[1][1], f0.x, f0.y);
    // P(2i)
    cmul(v[0][0], f1.x, f1.y); cmul(v[1][0], f1.x, f1.y);
    cmul(v[0][1], f1.z, f1.w); cmul(v[1][1], f1.z, f1.w);
    // E(2i+1)
    mmix(v[0][0], v[0][1], f0.z, f0.w);
    mmix(v[1][0], v[1][1], f0.z, f0.w);
    // O(2i)
    odd(f2, 0);
    // P(2i+1)
    cmul(v[0][0], f3.x, f3.y); cmul(v[1][0], f3.x, f3.y);
    cmul(v[0][1], f3.z, f3.w); cmul(v[1][1], f3.z, f3.w);
    // O(2i+1)
    odd(f4, 1);
  };

  // Pin
  {
    float4 a = *(const float4*)(g_io + R0);
    cmul(v[0][0], a.x, a.y); cmul(v[1][0], a.x, a.y);
    cmul(v[0][1], a.z, a.w); cmul(v[1][1], a.z, a.w);
  }

  const float4* P = g_pk + tid;   // step stride = 5*256 float4
  // prologue: prefetch steps 0 and 1
  float4 a0 = P[0],        a1 = P[256],        a2 = P[512],
         a3 = P[768],      a4 = P[1024];
  float4 b0 = P[1280],     b1 = P[1280+256],   b2 = P[1280+512],
         b3 = P[1280+768], b4 = P[1280+1024];

  #pragma unroll 1
  for (int i = 0; i < NSTEPS; i += 2) {
    const float4* Q = P + (i + 2) * 1280;     // pad steps make this safe
    float4 n0 = Q[0], n1 = Q[256], n2 = Q[512], n3 = Q[768], n4 = Q[1024];
    step(a0, a1, a2, a3, a4);
    a0 = n0; a1 = n1; a2 = n2; a3 = n3; a4 = n4;
    const float4* R = P + (i + 3) * 1280;
    n0 = R[0]; n1 = R[256]; n2 = R[512]; n3 = R[768]; n4 = R[1024];
    step(b0, b1, b2, b3, b4);
    b0 = n0; b1 = n1; b2 = n2; b3 = n3; b4 = n4;
  }

  // Pout
  {
    float4 a = *(const float4*)(g_io + 512 + R0);
    cmul(v[0][0], a.x, a.y); cmul(v[1][0], a.x, a.y);
    cmul(v[0][1], a.z, a.w); cmul(v[1][1], a.z, a.w);
  }

  if (write_complex) {
    float2* o = (float2*)out;
    #pragma unroll
    for (int c = 0; c < 2; ++c) {
      o[(R0 + 0) * NROWS + colbase + c] = v[c][0];
      o[(R0 + 1) * NROWS + colbase + c] = v[c][1];
    }
  } else {
    // d_out = 262144 floats: real part of the complex64 matrix
    #pragma unroll
    for (int c = 0; c < 2; ++c) {
      out[(R0 + 0) * NROWS + colbase + c] = v[c][0].x;
      out[(R0 + 1) * NROWS + colbase + c] = v[c][1].x;
    }
  }
}

// ---------------- launch ----------------

extern "C" void kernel_launch(void* const* d_in, const int* in_sizes, int n_in,
                              void* d_out, int out_size, void* d_ws, size_t ws_size,
                              hipStream_t stream) {
  const float* thf  = (const float*)d_in[0];  // thetas_full     (512,512)
  const float* thio = (const float*)d_in[1];  // thetas_inout    (2,512)
  const float* lpf  = (const float*)d_in[2];  // pc_losses_full  (512,512)
  const float* lpio = (const float*)d_in[3];  // pc_losses_inout (2,512)
  const float* le   = (const float*)d_in[4];  // mmi_losses_even (512,256)
  const float* lo   = (const float*)d_in[5];  // mmi_losses_odd  (512,255)
  const float* ie   = (const float*)d_in[6];  // mmi_imb_even    (512,256)
  const float* io2  = (const float*)d_in[7];  // mmi_imb_odd     (512,255)

  const int write_complex = (out_size >= 2 * NROWS * NROWS) ? 1 : 0;

  precomp_kernel<<<NSTEPS + 2, 256, 0, stream>>>(
      thf, thio, lpf, lpio, le, lo, ie, io2);
  prop_kernel<<<NROWS / 2, 256, 0, stream>>>((float*)d_out, write_complex);
}